// Round 12
// baseline (1693.459 us; speedup 1.0000x reference)
//
#include <hip/hip_runtime.h>

#define BB 8
#define LL 200
#define HH 128
#define NHEAD 4
#define HDIM 32
#define NBLK 2
#define BL (BB * LL)
#define NT 257            // TIME_SPAN+1
#define QT 8              // attn queries per tile
#define NQT 25            // 200/8
#define SSP 208           // attn score row stride
#define KTP 66            // attn KstT row stride
#define TSP 132           // GEMM tile row stride [r][k]
#define GRID 992          // <= 4 blocks/CU x 256 CU = 1024 slots (margin 32)
#define NTHR 256
#define NBAR 8

static constexpr float SQRT_H    = 11.313708498984761f;   // sqrt(128)
static constexpr float INV_SCALE = 0.17677669529663687f;  // 1/sqrt(32)
static constexpr float PADV      = -4294967295.0f;        // -2^32+1

struct P {
    const int *log_seqs, *tm, *pos, *neg;
    const float *item_emb, *posK, *posV, *timeK, *timeV;
    const float *attn_g, *attn_b;
    const float *Wq, *bq, *Wk, *bk, *Wv, *bv;
    const float *fwd_g, *fwd_b, *W1, *b1, *W2, *b2, *last_g, *last_b;
    float *seqs, *Qin, *Q, *K, *V, *att, *h1, *out;
    unsigned *bar;   // [NBAR counters][NBAR flags], zeroed per launch
};

// ---- software grid barrier (all GRID blocks resident by construction) ----
__device__ __forceinline__ void gbar(unsigned* bar, int i, int tid) {
    __syncthreads();
    if (tid == 0) {
        __threadfence();   // release: wb L2 so other XCDs see our stores
        unsigned old = __hip_atomic_fetch_add(&bar[i], 1u, __ATOMIC_ACQ_REL,
                                              __HIP_MEMORY_SCOPE_AGENT);
        if (old == GRID - 1) {
            __hip_atomic_store(&bar[NBAR + i], 1u, __ATOMIC_RELEASE,
                               __HIP_MEMORY_SCOPE_AGENT);
        } else {
            while (__hip_atomic_load(&bar[NBAR + i], __ATOMIC_ACQUIRE,
                                     __HIP_MEMORY_SCOPE_AGENT) == 0)
                __builtin_amdgcn_s_sleep(8);
        }
        __threadfence();   // acquire: invalidate L1/L2 before next phase reads
    }
    __syncthreads();
}

// ===== QKV tile: 32x16, tiles = 50 Mt x 24 Nt = 1200 ======================
__device__ __forceinline__ void qkv_tile(const P& p, int layer, int t, char* sm, int tid) {
    float* As = (float*)sm;            // 32*TSP
    float* Bs = As + 32 * TSP;         // 16*TSP
    int mt = t / 24, nt = t % 24;
    int matsel = nt >> 3;              // 0=Q 1=K 2=V
    int jb = (nt & 7) * 16;
    int row0 = mt * 32;
    const float* seqs_in = layer ? p.seqs : nullptr;
    const float* g   = p.attn_g + layer * HH;
    const float* bia = p.attn_b + layer * HH;
    const float* WQ = p.Wq + (size_t)layer * HH * HH;
    const float* WK = p.Wk + (size_t)layer * HH * HH;
    const float* WV = p.Wv + (size_t)layer * HH * HH;

    {   // stage A: 32 rows x 128, 8 threads/row; LN for Q-tiles
        int r = tid >> 3, seg = tid & 7;
        int row = row0 + r;
        float4 vv[4];
        if (seqs_in) {
            #pragma unroll
            for (int i = 0; i < 4; i++)
                vv[i] = *(const float4*)(seqs_in + (size_t)row * HH + seg * 16 + i * 4);
        } else {
            int idx = p.log_seqs[row];
            if (idx == 0) {
                #pragma unroll
                for (int i = 0; i < 4; i++) vv[i] = make_float4(0.f, 0.f, 0.f, 0.f);
            } else {
                #pragma unroll
                for (int i = 0; i < 4; i++) {
                    float4 e = *(const float4*)(p.item_emb + (size_t)idx * HH + seg * 16 + i * 4);
                    vv[i] = make_float4(e.x * SQRT_H, e.y * SQRT_H, e.z * SQRT_H, e.w * SQRT_H);
                }
            }
        }
        if (matsel == 0) {
            float s = 0.f, s2 = 0.f;
            #pragma unroll
            for (int i = 0; i < 4; i++) {
                s  += vv[i].x + vv[i].y + vv[i].z + vv[i].w;
                s2 += vv[i].x * vv[i].x + vv[i].y * vv[i].y + vv[i].z * vv[i].z + vv[i].w * vv[i].w;
            }
            #pragma unroll
            for (int off = 1; off < 8; off <<= 1) {
                s  += __shfl_xor(s, off);
                s2 += __shfl_xor(s2, off);
            }
            float mean = s * (1.f / HH);
            float var  = s2 * (1.f / HH) - mean * mean;
            float inv  = 1.f / sqrtf(var + 1e-8f);
            #pragma unroll
            for (int i = 0; i < 4; i++) {
                int k = seg * 16 + i * 4;
                float4 g4 = *(const float4*)(g + k);
                float4 b4 = *(const float4*)(bia + k);
                float4 y;
                y.x = (vv[i].x - mean) * inv * g4.x + b4.x;
                y.y = (vv[i].y - mean) * inv * g4.y + b4.y;
                y.z = (vv[i].z - mean) * inv * g4.z + b4.z;
                y.w = (vv[i].w - mean) * inv * g4.w + b4.w;
                *(float4*)&As[r * TSP + k] = y;
                if (nt == 0) *(float4*)(p.Qin + (size_t)row * HH + k) = y;
            }
        } else {
            #pragma unroll
            for (int i = 0; i < 4; i++)
                *(float4*)&As[r * TSP + seg * 16 + i * 4] = vv[i];
        }
    }
    {   // stage B: 16 W-rows x 128 k
        const float* W = (matsel == 0) ? WQ : (matsel == 1) ? WK : WV;
        int j = tid >> 4, seg = tid & 15;
        *(float4*)&Bs[j * TSP + seg * 8]     = *(const float4*)(W + (size_t)(jb + j) * HH + seg * 8);
        *(float4*)&Bs[j * TSP + seg * 8 + 4] = *(const float4*)(W + (size_t)(jb + j) * HH + seg * 8 + 4);
    }
    __syncthreads();

    int m = tid >> 3, jg = tid & 7;
    float acc0 = 0.f, acc1 = 0.f;
    const float* ar = &As[m * TSP];
    const float* b0r = &Bs[(jg * 2) * TSP];
    const float* b1r = &Bs[(jg * 2 + 1) * TSP];
    #pragma unroll 4
    for (int k4 = 0; k4 < 32; k4++) {
        float4 a = *(const float4*)(ar + k4 * 4);
        float4 b0 = *(const float4*)(b0r + k4 * 4);
        float4 b1 = *(const float4*)(b1r + k4 * 4);
        acc0 += a.x * b0.x + a.y * b0.y + a.z * b0.z + a.w * b0.w;
        acc1 += a.x * b1.x + a.y * b1.y + a.z * b1.z + a.w * b1.w;
    }
    int row = row0 + m;
    int col = jb + jg * 2;
    int l = row % LL;
    if (matsel == 0) {
        float2 bb = *(const float2*)(p.bq + layer * HH + col);
        *(float2*)(p.Q + (size_t)row * HH + col) =
            make_float2((acc0 + bb.x) * INV_SCALE, (acc1 + bb.y) * INV_SCALE);
    } else if (matsel == 1) {
        float2 bb = *(const float2*)(p.bk + layer * HH + col);
        float2 pk = *(const float2*)(p.posK + (size_t)l * HH + col);
        *(float2*)(p.K + (size_t)row * HH + col) =
            make_float2(acc0 + bb.x + pk.x, acc1 + bb.y + pk.y);
    } else {
        float2 bb = *(const float2*)(p.bv + layer * HH + col);
        float2 pv = *(const float2*)(p.posV + (size_t)l * HH + col);
        *(float2*)(p.V + (size_t)row * HH + col) =
            make_float2(acc0 + bb.x + pv.x, acc1 + bb.y + pv.y);
    }
    __syncthreads();
}

// ===== attention tile (R10-verified body): tiles = 800 =====================
__device__ __forceinline__ void attn_tile(const P& p, int t, char* sm, int tid) {
    float* Qs   = (float*)sm;                       // 256 f
    float* KstT = Qs + QT * HDIM;                   // 2112 f
    float* DTW  = KstT + HDIM * KTP;                // 2056 f
    float* Ssc  = DTW + QT * NT;                    // 1664 f
    float* Ost  = Ssc + QT * SSP;                   // 256 f
    unsigned short* tmst = (unsigned short*)(Ost + QT * HDIM);  // 1600 us

    int bn = t & 31;
    int b = bn >> 2, n = bn & 3;
    int qt = (NQT - 1) - (t >> 5);
    int q0 = qt * QT;
    int kmax = q0 + QT - 1;
    int wv = tid >> 6, ln = tid & 63;

    Ost[tid] = 0.f;
    if (tid < 64) {
        int qi = tid >> 3, d4 = tid & 7;
        *(float4*)(Qs + qi * HDIM + d4 * 4) =
            *(const float4*)(p.Q + ((size_t)(b * LL + q0 + qi)) * HH + n * HDIM + d4 * 4);
    }
    #pragma unroll
    for (int qi = 0; qi < QT; qi++)
        if (tid < LL)
            tmst[qi * LL + tid] = (unsigned short)p.tm[((size_t)(b * LL + q0 + qi)) * LL + tid];
    __syncthreads();

    int k2 = tid & 31, qi_c = tid >> 5;

    // DT[qi][tau] = Qh . timeKh[tau]
    for (int c = 0; c < 5; c++) {
        #pragma unroll
        for (int pp = 0; pp < 2; pp++) {
            int idx = tid + pp * 256;
            int r = idx >> 3, d4 = idx & 7;
            int tau = c * 64 + r;
            float4 w = make_float4(0.f, 0.f, 0.f, 0.f);
            if (tau < NT) w = *(const float4*)(p.timeK + (size_t)tau * HH + n * HDIM + d4 * 4);
            KstT[(d4 * 4 + 0) * KTP + r] = w.x;
            KstT[(d4 * 4 + 1) * KTP + r] = w.y;
            KstT[(d4 * 4 + 2) * KTP + r] = w.z;
            KstT[(d4 * 4 + 3) * KTP + r] = w.w;
        }
        __syncthreads();
        float a0 = 0.f, a1 = 0.f;
        #pragma unroll 4
        for (int d = 0; d < HDIM; d++) {
            float qv = Qs[qi_c * HDIM + d];
            float2 kv = *(const float2*)&KstT[d * KTP + k2 * 2];
            a0 += qv * kv.x; a1 += qv * kv.y;
        }
        int tau0 = c * 64 + k2 * 2;
        if (tau0 < NT)     DTW[qi_c * NT + tau0]     = a0;
        if (tau0 + 1 < NT) DTW[qi_c * NT + tau0 + 1] = a1;
        __syncthreads();
    }

    // S[qi][k] = Qh.Kh[k] + DT[qi][tm[k]], causal
    int nch = (kmax >> 6) + 1;
    for (int c = 0; c < nch; c++) {
        #pragma unroll
        for (int pp = 0; pp < 2; pp++) {
            int idx = tid + pp * 256;
            int r = idx >> 3, d4 = idx & 7;
            int k = c * 64 + r;
            float4 w = make_float4(0.f, 0.f, 0.f, 0.f);
            if (k < LL) w = *(const float4*)(p.K + ((size_t)(b * LL + k)) * HH + n * HDIM + d4 * 4);
            KstT[(d4 * 4 + 0) * KTP + r] = w.x;
            KstT[(d4 * 4 + 1) * KTP + r] = w.y;
            KstT[(d4 * 4 + 2) * KTP + r] = w.z;
            KstT[(d4 * 4 + 3) * KTP + r] = w.w;
        }
        __syncthreads();
        float a0 = 0.f, a1 = 0.f;
        #pragma unroll 4
        for (int d = 0; d < HDIM; d++) {
            float qv = Qs[qi_c * HDIM + d];
            float2 kv = *(const float2*)&KstT[d * KTP + k2 * 2];
            a0 += qv * kv.x; a1 += qv * kv.y;
        }
        int q = q0 + qi_c;
        int k0 = c * 64 + k2 * 2;
        if (k0 <= kmax)
            Ssc[qi_c * SSP + k0] = (k0 <= q) ? (a0 + DTW[qi_c * NT + tmst[qi_c * LL + k0]]) : PADV;
        if (k0 + 1 <= kmax)
            Ssc[qi_c * SSP + k0 + 1] = (k0 + 1 <= q) ? (a1 + DTW[qi_c * NT + tmst[qi_c * LL + k0 + 1]]) : PADV;
        __syncthreads();
    }

    for (int idx = tid; idx < QT * NT; idx += 256) DTW[idx] = 0.f;
    __syncthreads();

    // softmax + scatter W (DTW reused as bins)
    for (int rr = 0; rr < 2; rr++) {
        int qi = wv + rr * 4;
        int q = q0 + qi;
        float sv[4];
        float m = PADV;
        #pragma unroll
        for (int jj = 0; jj < 4; jj++) {
            int k = ln + 64 * jj;
            sv[jj] = (k <= q) ? Ssc[qi * SSP + k] : PADV;
            m = fmaxf(m, sv[jj]);
        }
        for (int off = 32; off; off >>= 1) m = fmaxf(m, __shfl_xor(m, off));
        float sum = 0.f;
        #pragma unroll
        for (int jj = 0; jj < 4; jj++) {
            int k = ln + 64 * jj;
            sv[jj] = (k <= q) ? __expf(sv[jj] - m) : 0.f;
            sum += sv[jj];
        }
        for (int off = 32; off; off >>= 1) sum += __shfl_xor(sum, off);
        float inv = 1.f / sum;
        #pragma unroll
        for (int jj = 0; jj < 4; jj++) {
            int k = ln + 64 * jj;
            float pr = sv[jj] * inv;
            if (k < SSP) Ssc[qi * SSP + k] = (k <= q) ? pr : 0.f;
            if (k <= q) atomicAdd(&DTW[qi * NT + tmst[qi * LL + k]], pr);
        }
    }
    __syncthreads();

    // O = P@Vh + W@timeVh
    int d = tid & 31, kg = tid >> 5;
    float acc[QT] = {0,0,0,0,0,0,0,0};
    const float* vb = p.V + ((size_t)(b * LL)) * HH + n * HDIM + d;
    for (int k = kg; k <= kmax; k += 8) {
        float v = vb[(size_t)k * HH];
        #pragma unroll
        for (int qi = 0; qi < QT; qi++) acc[qi] += Ssc[qi * SSP + k] * v;
    }
    const float* tvb = p.timeV + n * HDIM + d;
    for (int tt = kg; tt < NT; tt += 8) {
        float v = tvb[(size_t)tt * HH];
        #pragma unroll
        for (int qi = 0; qi < QT; qi++) acc[qi] += DTW[qi * NT + tt] * v;
    }
    #pragma unroll
    for (int qi = 0; qi < QT; qi++) atomicAdd(&Ost[qi * HDIM + d], acc[qi]);
    __syncthreads();
    {
        int qi = tid >> 5;
        p.att[((size_t)(b * LL + q0 + qi)) * HH + n * HDIM + (tid & 31)] = Ost[tid];
    }
    __syncthreads();
}

// ===== FF1 tile: 16x16, tiles = 800 =======================================
__device__ __forceinline__ void ff1_tile(const P& p, int layer, int t, char* sm, int tid) {
    float* As = (float*)sm;
    float* Bs = As + 16 * TSP;
    int mt = t >> 3, jb = (t & 7) * 16;
    int row0 = mt * 16;
    const float* g   = p.fwd_g + layer * HH;
    const float* bia = p.fwd_b + layer * HH;
    const float* W1  = p.W1 + (size_t)layer * HH * HH;

    {   // stage A = LN(Qin+att), 16 threads/row
        int r = tid >> 4, seg = tid & 15;
        int row = row0 + r;
        float4 vv[2];
        #pragma unroll
        for (int i = 0; i < 2; i++) {
            int k = seg * 8 + i * 4;
            float4 q4 = *(const float4*)(p.Qin + (size_t)row * HH + k);
            float4 a4 = *(const float4*)(p.att + (size_t)row * HH + k);
            vv[i] = make_float4(q4.x + a4.x, q4.y + a4.y, q4.z + a4.z, q4.w + a4.w);
        }
        float s = 0.f, s2 = 0.f;
        #pragma unroll
        for (int i = 0; i < 2; i++) {
            s  += vv[i].x + vv[i].y + vv[i].z + vv[i].w;
            s2 += vv[i].x * vv[i].x + vv[i].y * vv[i].y + vv[i].z * vv[i].z + vv[i].w * vv[i].w;
        }
        #pragma unroll
        for (int off = 1; off < 16; off <<= 1) {
            s  += __shfl_xor(s, off);
            s2 += __shfl_xor(s2, off);
        }
        float mean = s * (1.f / HH);
        float var  = s2 * (1.f / HH) - mean * mean;
        float inv  = 1.f / sqrtf(var + 1e-8f);
        #pragma unroll
        for (int i = 0; i < 2; i++) {
            int k = seg * 8 + i * 4;
            float4 g4 = *(const float4*)(g + k);
            float4 b4 = *(const float4*)(bia + k);
            float4 y;
            y.x = (vv[i].x - mean) * inv * g4.x + b4.x;
            y.y = (vv[i].y - mean) * inv * g4.y + b4.y;
            y.z = (vv[i].z - mean) * inv * g4.z + b4.z;
            y.w = (vv[i].w - mean) * inv * g4.w + b4.w;
            *(float4*)&As[r * TSP + k] = y;
        }
    }
    {   // stage B
        int j = tid >> 4, seg = tid & 15;
        *(float4*)&Bs[j * TSP + seg * 8]     = *(const float4*)(W1 + (size_t)(jb + j) * HH + seg * 8);
        *(float4*)&Bs[j * TSP + seg * 8 + 4] = *(const float4*)(W1 + (size_t)(jb + j) * HH + seg * 8 + 4);
    }
    __syncthreads();

    int m = tid >> 4, j = tid & 15;
    float acc = 0.f;
    const float* ar = &As[m * TSP];
    const float* br = &Bs[j * TSP];
    #pragma unroll 4
    for (int k4 = 0; k4 < 32; k4++) {
        float4 a = *(const float4*)(ar + k4 * 4);
        float4 b = *(const float4*)(br + k4 * 4);
        acc += a.x * b.x + a.y * b.y + a.z * b.z + a.w * b.w;
    }
    int col = jb + j;
    float tt = acc + p.b1[layer * HH + col];
    p.h1[(size_t)(row0 + m) * HH + col] = tt > 0.f ? tt : 0.f;
    __syncthreads();
}

// ===== FF2 tile: 16x16, tiles = 800 =======================================
__device__ __forceinline__ void ff2_tile(const P& p, int layer, int t, char* sm, int tid) {
    float* As = (float*)sm;
    float* Bs = As + 16 * TSP;
    float* mu = Bs + 16 * TSP;
    float* rstd = mu + 16;
    int mt = t >> 3, jb = (t & 7) * 16;
    int row0 = mt * 16;
    const float* g   = p.fwd_g + layer * HH;
    const float* bia = p.fwd_b + layer * HH;
    const float* W2  = p.W2 + (size_t)layer * HH * HH;

    {   // stage A = h1; residual row stats
        int r = tid >> 4, seg = tid & 15;
        int row = row0 + r;
        #pragma unroll
        for (int i = 0; i < 2; i++) {
            int k = seg * 8 + i * 4;
            *(float4*)&As[r * TSP + k] = *(const float4*)(p.h1 + (size_t)row * HH + k);
        }
        float s = 0.f, s2 = 0.f;
        #pragma unroll
        for (int i = 0; i < 2; i++) {
            int k = seg * 8 + i * 4;
            float4 q4 = *(const float4*)(p.Qin + (size_t)row * HH + k);
            float4 a4 = *(const float4*)(p.att + (size_t)row * HH + k);
            float4 v = make_float4(q4.x + a4.x, q4.y + a4.y, q4.z + a4.z, q4.w + a4.w);
            s  += v.x + v.y + v.z + v.w;
            s2 += v.x * v.x + v.y * v.y + v.z * v.z + v.w * v.w;
        }
        #pragma unroll
        for (int off = 1; off < 16; off <<= 1) {
            s  += __shfl_xor(s, off);
            s2 += __shfl_xor(s2, off);
        }
        float mean = s * (1.f / HH);
        float var  = s2 * (1.f / HH) - mean * mean;
        if (seg == 0) { mu[r] = mean; rstd[r] = 1.f / sqrtf(var + 1e-8f); }
    }
    {   // stage B
        int j = tid >> 4, seg = tid & 15;
        *(float4*)&Bs[j * TSP + seg * 8]     = *(const float4*)(W2 + (size_t)(jb + j) * HH + seg * 8);
        *(float4*)&Bs[j * TSP + seg * 8 + 4] = *(const float4*)(W2 + (size_t)(jb + j) * HH + seg * 8 + 4);
    }
    __syncthreads();

    int m = tid >> 4, j = tid & 15;
    float acc = 0.f;
    const float* ar = &As[m * TSP];
    const float* br = &Bs[j * TSP];
    #pragma unroll 4
    for (int k4 = 0; k4 < 32; k4++) {
        float4 a = *(const float4*)(ar + k4 * 4);
        float4 b = *(const float4*)(br + k4 * 4);
        acc += a.x * b.x + a.y * b.y + a.z * b.z + a.w * b.w;
    }
    int row = row0 + m;
    int col = jb + j;
    float resid = p.Qin[(size_t)row * HH + col] + p.att[(size_t)row * HH + col];
    float y = (resid - mu[m]) * rstd[m] * g[col] + bia[col];
    float o = acc + p.b2[layer * HH + col] + y;
    if (p.log_seqs[row] == 0) o = 0.f;
    p.seqs[(size_t)row * HH + col] = o;
    __syncthreads();
}

// ===== last-LN + logits for one row (256 thr; halves duplicate) ===========
__device__ __forceinline__ void lnlog_row(const P& p, int row, char* sm, int tid) {
    float* r1 = (float*)sm;        // [2]
    float* r2 = r1 + 2;
    float* rp = r1 + 4;
    float* rn = r1 + 6;
    int h = tid & 127;
    float v = p.seqs[(size_t)row * HH + h];
    float s = v, s2 = v * v;
    for (int off = 32; off; off >>= 1) {
        s  += __shfl_xor(s, off);
        s2 += __shfl_xor(s2, off);
    }
    if ((h & 63) == 0 && tid < 128) { r1[h >> 6] = s; r2[h >> 6] = s2; }
    __syncthreads();
    float mean = (r1[0] + r1[1]) * (1.f / HH);
    float var  = (r2[0] + r2[1]) * (1.f / HH) - mean * mean;
    float inv = 1.f / sqrtf(var + 1e-8f);
    float f = (v - mean) * inv * p.last_g[h] + p.last_b[h];

    int ip = p.pos[row], in_ = p.neg[row];
    float vp = f * p.item_emb[(size_t)ip * HH + h];
    float vn = f * p.item_emb[(size_t)in_ * HH + h];
    for (int off = 32; off; off >>= 1) {
        vp += __shfl_xor(vp, off);
        vn += __shfl_xor(vn, off);
    }
    if ((h & 63) == 0 && tid < 128) { rp[h >> 6] = vp; rn[h >> 6] = vn; }
    __syncthreads();
    if (tid == 0) {
        p.out[row]      = rp[0] + rp[1];
        p.out[BL + row] = rn[0] + rn[1];
    }
    __syncthreads();
}

// ===== mega kernel: all phases, software grid barrier between =============
__global__ __launch_bounds__(NTHR, 4) void mega(P p) {
    __shared__ __align__(16) char sm[28608];
    int blk = blockIdx.x, tid = threadIdx.x;

    for (int layer = 0; layer < NBLK; layer++) {
        for (int t = blk; t < 1200; t += GRID) qkv_tile(p, layer, t, sm, tid);
        gbar(p.bar, layer * 4 + 0, tid);
        if (blk < NQT * 32) attn_tile(p, blk, sm, tid);
        gbar(p.bar, layer * 4 + 1, tid);
        if (blk < 800) ff1_tile(p, layer, blk, sm, tid);
        gbar(p.bar, layer * 4 + 2, tid);
        if (blk < 800) ff2_tile(p, layer, blk, sm, tid);
        gbar(p.bar, layer * 4 + 3, tid);
    }
    for (int row = blk; row < BL; row += GRID) lnlog_row(p, row, sm, tid);
}

extern "C" void kernel_launch(void* const* d_in, const int* in_sizes, int n_in,
                              void* d_out, int out_size, void* d_ws, size_t ws_size,
                              hipStream_t stream) {
    P h;
    h.log_seqs = (const int*)d_in[1];
    h.tm       = (const int*)d_in[2];
    h.pos      = (const int*)d_in[3];
    h.neg      = (const int*)d_in[4];
    h.item_emb = (const float*)d_in[5];
    h.posK     = (const float*)d_in[6];
    h.posV     = (const float*)d_in[7];
    h.timeK    = (const float*)d_in[8];
    h.timeV    = (const float*)d_in[9];
    h.attn_g   = (const float*)d_in[10];
    h.attn_b   = (const float*)d_in[11];
    h.Wq       = (const float*)d_in[12];
    h.bq       = (const float*)d_in[13];
    h.Wk       = (const float*)d_in[14];
    h.bk       = (const float*)d_in[15];
    h.Wv       = (const float*)d_in[16];
    h.bv       = (const float*)d_in[17];
    h.fwd_g    = (const float*)d_in[18];
    h.fwd_b    = (const float*)d_in[19];
    h.W1       = (const float*)d_in[20];
    h.b1       = (const float*)d_in[21];
    h.W2       = (const float*)d_in[22];
    h.b2       = (const float*)d_in[23];
    h.last_g   = (const float*)d_in[24];
    h.last_b   = (const float*)d_in[25];

    float* seqs = (float*)d_ws;            // 7 x B*L*H f32 + barrier words
    h.seqs = seqs;
    h.Qin  = seqs + (size_t)BL * HH;
    h.Q    = h.Qin + (size_t)BL * HH;
    h.K    = h.Q   + (size_t)BL * HH;
    h.V    = h.K   + (size_t)BL * HH;
    h.att  = h.V   + (size_t)BL * HH;
    h.h1   = h.att + (size_t)BL * HH;
    h.out  = (float*)d_out;
    h.bar  = (unsigned*)(h.h1 + (size_t)BL * HH);

    hipMemsetAsync(h.bar, 0, 2 * NBAR * sizeof(unsigned), stream);
    mega<<<dim3(GRID), dim3(NTHR), 0, stream>>>(h);
}

// Round 13
// 239.819 us; speedup vs baseline: 7.0614x; 7.0614x over previous
//
#include <hip/hip_runtime.h>

#define BB 8
#define LL 200
#define HH 128
#define NHEAD 4
#define HDIM 32
#define NBLK 2
#define BL (BB * LL)
#define NT 257            // TIME_SPAN+1
#define QT 8              // attn queries per tile
#define NQT 25            // 200/8
#define SSP 208           // attn score row stride
#define KTP 66            // attn KstT row stride
#define TSP 132           // GEMM tile row stride [r][k]

static constexpr float SQRT_H    = 11.313708498984761f;   // sqrt(128)
static constexpr float INV_SCALE = 0.17677669529663687f;  // 1/sqrt(32)
static constexpr float PADV      = -4294967295.0f;        // -2^32+1

// ===== QKV GEMM: 32x16 tiles, 50 Mt x 24 Nt = 1200 blocks, 256 thr ========
__global__ void k_qkv_gemm(const float* __restrict__ seqs_in,
                           const int* __restrict__ log_seqs,
                           const float* __restrict__ item_emb,
                           const float* __restrict__ g, const float* __restrict__ bia,
                           const float* __restrict__ Wq, const float* __restrict__ bq,
                           const float* __restrict__ Wk, const float* __restrict__ bk,
                           const float* __restrict__ Wv, const float* __restrict__ bv,
                           const float* __restrict__ posK, const float* __restrict__ posV,
                           float* __restrict__ Qin, float* __restrict__ Q,
                           float* __restrict__ K, float* __restrict__ V) {
    int mt = blockIdx.x / 24, nt = blockIdx.x % 24;
    int matsel = nt >> 3;              // 0=Q 1=K 2=V
    int jb = (nt & 7) * 16;
    int row0 = mt * 32;
    int tid = threadIdx.x;
    __shared__ float As[32 * TSP];
    __shared__ float Bs[16 * TSP];

    {   // stage A: 32 rows x 128, 8 threads/row; LN for Q-tiles
        int r = tid >> 3, seg = tid & 7;
        int row = row0 + r;
        float4 vv[4];
        if (seqs_in) {
            #pragma unroll
            for (int i = 0; i < 4; i++)
                vv[i] = *(const float4*)(seqs_in + (size_t)row * HH + seg * 16 + i * 4);
        } else {
            int idx = log_seqs[row];
            if (idx == 0) {
                #pragma unroll
                for (int i = 0; i < 4; i++) vv[i] = make_float4(0.f, 0.f, 0.f, 0.f);
            } else {
                #pragma unroll
                for (int i = 0; i < 4; i++) {
                    float4 e = *(const float4*)(item_emb + (size_t)idx * HH + seg * 16 + i * 4);
                    vv[i] = make_float4(e.x * SQRT_H, e.y * SQRT_H, e.z * SQRT_H, e.w * SQRT_H);
                }
            }
        }
        if (matsel == 0) {
            float s = 0.f, s2 = 0.f;
            #pragma unroll
            for (int i = 0; i < 4; i++) {
                s  += vv[i].x + vv[i].y + vv[i].z + vv[i].w;
                s2 += vv[i].x * vv[i].x + vv[i].y * vv[i].y + vv[i].z * vv[i].z + vv[i].w * vv[i].w;
            }
            #pragma unroll
            for (int off = 1; off < 8; off <<= 1) {
                s  += __shfl_xor(s, off);
                s2 += __shfl_xor(s2, off);
            }
            float mean = s * (1.f / HH);
            float var  = s2 * (1.f / HH) - mean * mean;
            float inv  = 1.f / sqrtf(var + 1e-8f);
            #pragma unroll
            for (int i = 0; i < 4; i++) {
                int k = seg * 16 + i * 4;
                float4 g4 = *(const float4*)(g + k);
                float4 b4 = *(const float4*)(bia + k);
                float4 y;
                y.x = (vv[i].x - mean) * inv * g4.x + b4.x;
                y.y = (vv[i].y - mean) * inv * g4.y + b4.y;
                y.z = (vv[i].z - mean) * inv * g4.z + b4.z;
                y.w = (vv[i].w - mean) * inv * g4.w + b4.w;
                *(float4*)&As[r * TSP + k] = y;
                if (nt == 0) *(float4*)(Qin + (size_t)row * HH + k) = y;
            }
        } else {
            #pragma unroll
            for (int i = 0; i < 4; i++)
                *(float4*)&As[r * TSP + seg * 16 + i * 4] = vv[i];
        }
    }
    {   // stage B: 16 W-rows x 128 k
        const float* W = (matsel == 0) ? Wq : (matsel == 1) ? Wk : Wv;
        int j = tid >> 4, seg = tid & 15;
        *(float4*)&Bs[j * TSP + seg * 8]     = *(const float4*)(W + (size_t)(jb + j) * HH + seg * 8);
        *(float4*)&Bs[j * TSP + seg * 8 + 4] = *(const float4*)(W + (size_t)(jb + j) * HH + seg * 8 + 4);
    }
    __syncthreads();

    int m = tid >> 3, jg = tid & 7;
    float acc0 = 0.f, acc1 = 0.f;
    const float* ar = &As[m * TSP];
    const float* b0r = &Bs[(jg * 2) * TSP];
    const float* b1r = &Bs[(jg * 2 + 1) * TSP];
    #pragma unroll 4
    for (int k4 = 0; k4 < 32; k4++) {
        float4 a = *(const float4*)(ar + k4 * 4);
        float4 b0 = *(const float4*)(b0r + k4 * 4);
        float4 b1 = *(const float4*)(b1r + k4 * 4);
        acc0 += a.x * b0.x + a.y * b0.y + a.z * b0.z + a.w * b0.w;
        acc1 += a.x * b1.x + a.y * b1.y + a.z * b1.z + a.w * b1.w;
    }
    int row = row0 + m;
    int col = jb + jg * 2;
    int l = row % LL;
    if (matsel == 0) {
        float2 bb = *(const float2*)(bq + col);
        *(float2*)(Q + (size_t)row * HH + col) =
            make_float2((acc0 + bb.x) * INV_SCALE, (acc1 + bb.y) * INV_SCALE);
    } else if (matsel == 1) {
        float2 bb = *(const float2*)(bk + col);
        float2 pk = *(const float2*)(posK + (size_t)l * HH + col);
        *(float2*)(K + (size_t)row * HH + col) =
            make_float2(acc0 + bb.x + pk.x, acc1 + bb.y + pk.y);
    } else {
        float2 bb = *(const float2*)(bv + col);
        float2 pv = *(const float2*)(posV + (size_t)l * HH + col);
        *(float2*)(V + (size_t)row * HH + col) =
            make_float2(acc0 + bb.x + pv.x, acc1 + bb.y + pv.y);
    }
}

// ===== attention v6: double-buffered unified staging, ~13 barriers ========
__global__ void k_attn(const float* __restrict__ Q, const float* __restrict__ K,
                       const float* __restrict__ V,
                       const float* __restrict__ timeK, const float* __restrict__ timeV,
                       const int* __restrict__ tm,
                       float* __restrict__ att) {
    int bn = blockIdx.x & 31;
    int b = bn >> 2, n = bn & 3;
    int qt = (NQT - 1) - (blockIdx.x >> 5);   // heavy tiles first
    int q0 = qt * QT;
    int kmax = q0 + QT - 1;
    int tid = threadIdx.x;
    int wv = tid >> 6, ln = tid & 63;

    __shared__ float Qs[QT * HDIM];            // 1 KB
    __shared__ float KstT[2][HDIM * KTP];      // 16.5 KB (double buffer)
    __shared__ float DTW[QT * NT];             // 8.2 KB
    __shared__ float Ssc[QT * SSP];            // 6.7 KB
    __shared__ unsigned short tmst[QT * LL];   // 3.2 KB
    __shared__ float Ost[QT * HDIM];           // 1 KB
    // ~36.6 KB -> 4 blocks/CU

    int nchS = (kmax >> 6) + 1;   // S chunks
    int ntot = 5 + nchS;          // 5 DT chunks + S chunks

    // stage chunk c into buffer buf: DT rows (c<5) or K rows (c>=5)
    auto stage = [&](int c, int buf) {
        const float* src;
        int base, lim;
        if (c < 5) { base = c * 64; src = timeK; lim = NT; }
        else       { base = (c - 5) * 64; src = K + ((size_t)(b * LL)) * HH; lim = LL; }
        #pragma unroll
        for (int pp = 0; pp < 2; pp++) {
            int idx = tid + pp * 256;
            int r = idx >> 3, d4 = idx & 7;
            int rr = base + r;
            float4 w = make_float4(0.f, 0.f, 0.f, 0.f);
            if (rr < lim) w = *(const float4*)(src + (size_t)rr * HH + n * HDIM + d4 * 4);
            KstT[buf][(d4 * 4 + 0) * KTP + r] = w.x;
            KstT[buf][(d4 * 4 + 1) * KTP + r] = w.y;
            KstT[buf][(d4 * 4 + 2) * KTP + r] = w.z;
            KstT[buf][(d4 * 4 + 3) * KTP + r] = w.w;
        }
    };

    // ---- initial: Q tile, tm tile, zero Ost, stage chunk 0 ----
    Ost[tid] = 0.f;
    if (tid < 64) {
        int qi = tid >> 3, d4 = tid & 7;
        *(float4*)(Qs + qi * HDIM + d4 * 4) =
            *(const float4*)(Q + ((size_t)(b * LL + q0 + qi)) * HH + n * HDIM + d4 * 4);
    }
    #pragma unroll
    for (int qi = 0; qi < QT; qi++)
        if (tid < LL)
            tmst[qi * LL + tid] = (unsigned short)tm[((size_t)(b * LL + q0 + qi)) * LL + tid];
    stage(0, 0);
    __syncthreads();

    int k2 = tid & 31, qi_c = tid >> 5;

    // ---- pipelined chunk loop: 1 barrier per chunk ----
    for (int c = 0; c < ntot; c++) {
        int buf = c & 1;
        if (c + 1 < ntot) stage(c + 1, buf ^ 1);
        float a0 = 0.f, a1 = 0.f;
        #pragma unroll 4
        for (int d = 0; d < HDIM; d++) {
            float qv = Qs[qi_c * HDIM + d];
            float2 kv = *(const float2*)&KstT[buf][d * KTP + k2 * 2];
            a0 += qv * kv.x; a1 += qv * kv.y;
        }
        if (c < 5) {
            int tau0 = c * 64 + k2 * 2;
            if (tau0 < NT)     DTW[qi_c * NT + tau0]     = a0;
            if (tau0 + 1 < NT) DTW[qi_c * NT + tau0 + 1] = a1;
        } else {
            int q = q0 + qi_c;
            int k0 = (c - 5) * 64 + k2 * 2;
            if (k0 <= kmax)
                Ssc[qi_c * SSP + k0] = (k0 <= q) ? (a0 + DTW[qi_c * NT + tmst[qi_c * LL + k0]]) : PADV;
            if (k0 + 1 <= kmax)
                Ssc[qi_c * SSP + k0 + 1] = (k0 + 1 <= q) ? (a1 + DTW[qi_c * NT + tmst[qi_c * LL + k0 + 1]]) : PADV;
        }
        __syncthreads();
    }

    // ---- zero bins (DTW reused) ----
    for (int idx = tid; idx < QT * NT; idx += 256) DTW[idx] = 0.f;
    __syncthreads();

    // ---- softmax + scatter W ----
    for (int rr = 0; rr < 2; rr++) {
        int qi = wv + rr * 4;
        int q = q0 + qi;
        float sv[4];
        float m = PADV;
        #pragma unroll
        for (int jj = 0; jj < 4; jj++) {
            int k = ln + 64 * jj;
            sv[jj] = (k <= q) ? Ssc[qi * SSP + k] : PADV;
            m = fmaxf(m, sv[jj]);
        }
        for (int off = 32; off; off >>= 1) m = fmaxf(m, __shfl_xor(m, off));
        float sum = 0.f;
        #pragma unroll
        for (int jj = 0; jj < 4; jj++) {
            int k = ln + 64 * jj;
            sv[jj] = (k <= q) ? __expf(sv[jj] - m) : 0.f;
            sum += sv[jj];
        }
        for (int off = 32; off; off >>= 1) sum += __shfl_xor(sum, off);
        float inv = 1.f / sum;
        #pragma unroll
        for (int jj = 0; jj < 4; jj++) {
            int k = ln + 64 * jj;
            float pr = sv[jj] * inv;
            if (k < SSP) Ssc[qi * SSP + k] = (k <= q) ? pr : 0.f;
            if (k <= q) atomicAdd(&DTW[qi * NT + tmst[qi * LL + k]], pr);
        }
    }
    __syncthreads();

    // ---- O = P@Vh + W@timeVh ----
    int d = tid & 31, kg = tid >> 5;
    float acc[QT] = {0,0,0,0,0,0,0,0};
    const float* vb = V + ((size_t)(b * LL)) * HH + n * HDIM + d;
    for (int k = kg; k <= kmax; k += 8) {
        float v = vb[(size_t)k * HH];
        #pragma unroll
        for (int qi = 0; qi < QT; qi++) acc[qi] += Ssc[qi * SSP + k] * v;
    }
    const float* tvb = timeV + n * HDIM + d;
    for (int t = kg; t < NT; t += 8) {
        float v = tvb[(size_t)t * HH];
        #pragma unroll
        for (int qi = 0; qi < QT; qi++) acc[qi] += DTW[qi * NT + t] * v;
    }
    #pragma unroll
    for (int qi = 0; qi < QT; qi++) atomicAdd(&Ost[qi * HDIM + d], acc[qi]);
    __syncthreads();
    {
        int qi = tid >> 5;
        att[((size_t)(b * LL + q0 + qi)) * HH + n * HDIM + (tid & 31)] = Ost[tid];
    }
}

// ===== FF1: h1 = relu(LN(Qin+att)@W1^T + b1), 16x16 tiles, 800 blocks =====
__global__ void k_ff1(const float* __restrict__ Qin, const float* __restrict__ att,
                      const float* __restrict__ g, const float* __restrict__ bia,
                      const float* __restrict__ W1, const float* __restrict__ b1,
                      float* __restrict__ h1) {
    int mt = blockIdx.x >> 3, jb = (blockIdx.x & 7) * 16;
    int row0 = mt * 16;
    int tid = threadIdx.x;
    __shared__ float As[16 * TSP];
    __shared__ float Bs[16 * TSP];

    {   // stage A = LN(Qin+att), 16 threads/row
        int r = tid >> 4, seg = tid & 15;
        int row = row0 + r;
        float4 vv[2];
        #pragma unroll
        for (int i = 0; i < 2; i++) {
            int k = seg * 8 + i * 4;
            float4 q4 = *(const float4*)(Qin + (size_t)row * HH + k);
            float4 a4 = *(const float4*)(att + (size_t)row * HH + k);
            vv[i] = make_float4(q4.x + a4.x, q4.y + a4.y, q4.z + a4.z, q4.w + a4.w);
        }
        float s = 0.f, s2 = 0.f;
        #pragma unroll
        for (int i = 0; i < 2; i++) {
            s  += vv[i].x + vv[i].y + vv[i].z + vv[i].w;
            s2 += vv[i].x * vv[i].x + vv[i].y * vv[i].y + vv[i].z * vv[i].z + vv[i].w * vv[i].w;
        }
        #pragma unroll
        for (int off = 1; off < 16; off <<= 1) {
            s  += __shfl_xor(s, off);
            s2 += __shfl_xor(s2, off);
        }
        float mean = s * (1.f / HH);
        float var  = s2 * (1.f / HH) - mean * mean;
        float inv  = 1.f / sqrtf(var + 1e-8f);
        #pragma unroll
        for (int i = 0; i < 2; i++) {
            int k = seg * 8 + i * 4;
            float4 g4 = *(const float4*)(g + k);
            float4 b4 = *(const float4*)(bia + k);
            float4 y;
            y.x = (vv[i].x - mean) * inv * g4.x + b4.x;
            y.y = (vv[i].y - mean) * inv * g4.y + b4.y;
            y.z = (vv[i].z - mean) * inv * g4.z + b4.z;
            y.w = (vv[i].w - mean) * inv * g4.w + b4.w;
            *(float4*)&As[r * TSP + k] = y;
        }
    }
    {   // stage B
        int j = tid >> 4, seg = tid & 15;
        *(float4*)&Bs[j * TSP + seg * 8]     = *(const float4*)(W1 + (size_t)(jb + j) * HH + seg * 8);
        *(float4*)&Bs[j * TSP + seg * 8 + 4] = *(const float4*)(W1 + (size_t)(jb + j) * HH + seg * 8 + 4);
    }
    __syncthreads();

    int m = tid >> 4, j = tid & 15;
    float acc = 0.f;
    const float* ar = &As[m * TSP];
    const float* br = &Bs[j * TSP];
    #pragma unroll 4
    for (int k4 = 0; k4 < 32; k4++) {
        float4 a = *(const float4*)(ar + k4 * 4);
        float4 b = *(const float4*)(br + k4 * 4);
        acc += a.x * b.x + a.y * b.y + a.z * b.z + a.w * b.w;
    }
    int col = jb + j;
    float t = acc + b1[col];
    h1[(size_t)(row0 + m) * HH + col] = t > 0.f ? t : 0.f;
}

// ===== FF2: out = (h1@W2^T + b2 + LN(Qin+att))*keep, 16x16, 800 blocks ====
__global__ void k_ff2(const float* __restrict__ h1,
                      const float* __restrict__ Qin, const float* __restrict__ att,
                      const float* __restrict__ g, const float* __restrict__ bia,
                      const float* __restrict__ W2, const float* __restrict__ b2,
                      const int* __restrict__ log_seqs,
                      float* __restrict__ out) {
    int mt = blockIdx.x >> 3, jb = (blockIdx.x & 7) * 16;
    int row0 = mt * 16;
    int tid = threadIdx.x;
    __shared__ float As[16 * TSP];
    __shared__ float Bs[16 * TSP];
    __shared__ float mu[16], rstd[16];

    {   // stage A = h1; compute residual row stats
        int r = tid >> 4, seg = tid & 15;
        int row = row0 + r;
        #pragma unroll
        for (int i = 0; i < 2; i++) {
            int k = seg * 8 + i * 4;
            *(float4*)&As[r * TSP + k] = *(const float4*)(h1 + (size_t)row * HH + k);
        }
        float s = 0.f, s2 = 0.f;
        #pragma unroll
        for (int i = 0; i < 2; i++) {
            int k = seg * 8 + i * 4;
            float4 q4 = *(const float4*)(Qin + (size_t)row * HH + k);
            float4 a4 = *(const float4*)(att + (size_t)row * HH + k);
            float4 v = make_float4(q4.x + a4.x, q4.y + a4.y, q4.z + a4.z, q4.w + a4.w);
            s  += v.x + v.y + v.z + v.w;
            s2 += v.x * v.x + v.y * v.y + v.z * v.z + v.w * v.w;
        }
        #pragma unroll
        for (int off = 1; off < 16; off <<= 1) {
            s  += __shfl_xor(s, off);
            s2 += __shfl_xor(s2, off);
        }
        float mean = s * (1.f / HH);
        float var  = s2 * (1.f / HH) - mean * mean;
        if (seg == 0) { mu[r] = mean; rstd[r] = 1.f / sqrtf(var + 1e-8f); }
    }
    {   // stage B
        int j = tid >> 4, seg = tid & 15;
        *(float4*)&Bs[j * TSP + seg * 8]     = *(const float4*)(W2 + (size_t)(jb + j) * HH + seg * 8);
        *(float4*)&Bs[j * TSP + seg * 8 + 4] = *(const float4*)(W2 + (size_t)(jb + j) * HH + seg * 8 + 4);
    }
    __syncthreads();

    int m = tid >> 4, j = tid & 15;
    float acc = 0.f;
    const float* ar = &As[m * TSP];
    const float* br = &Bs[j * TSP];
    #pragma unroll 4
    for (int k4 = 0; k4 < 32; k4++) {
        float4 a = *(const float4*)(ar + k4 * 4);
        float4 b = *(const float4*)(br + k4 * 4);
        acc += a.x * b.x + a.y * b.y + a.z * b.z + a.w * b.w;
    }
    int row = row0 + m;
    int col = jb + j;
    float resid = Qin[(size_t)row * HH + col] + att[(size_t)row * HH + col];
    float y = (resid - mu[m]) * rstd[m] * g[col] + bia[col];
    float o = acc + b2[col] + y;
    if (log_seqs[row] == 0) o = 0.f;
    out[(size_t)row * HH + col] = o;
}

// ===== fused last-LN + pos/neg logits: one block per row ==================
__global__ void k_lnlogits(const float* __restrict__ seqs,
                           const float* __restrict__ g, const float* __restrict__ bia,
                           const float* __restrict__ item_emb,
                           const int* __restrict__ pos, const int* __restrict__ neg,
                           float* __restrict__ out) {
    int row = blockIdx.x;
    int h = threadIdx.x;
    float v = seqs[(size_t)row * HH + h];
    float s = v, s2 = v * v;
    for (int off = 32; off; off >>= 1) {
        s  += __shfl_xor(s, off);
        s2 += __shfl_xor(s2, off);
    }
    __shared__ float r1[2], r2[2];
    if ((h & 63) == 0) { r1[h >> 6] = s; r2[h >> 6] = s2; }
    __syncthreads();
    float mean = (r1[0] + r1[1]) * (1.f / HH);
    float var  = (r2[0] + r2[1]) * (1.f / HH) - mean * mean;
    float inv = 1.f / sqrtf(var + 1e-8f);
    float f = (v - mean) * inv * g[h] + bia[h];

    int ip = pos[row], in_ = neg[row];
    float vp = f * item_emb[(size_t)ip * HH + h];
    float vn = f * item_emb[(size_t)in_ * HH + h];
    for (int off = 32; off; off >>= 1) {
        vp += __shfl_xor(vp, off);
        vn += __shfl_xor(vn, off);
    }
    __shared__ float rp[2], rn[2];
    if ((h & 63) == 0) { rp[h >> 6] = vp; rn[h >> 6] = vn; }
    __syncthreads();
    if (h == 0) {
        out[row]      = rp[0] + rp[1];
        out[BL + row] = rn[0] + rn[1];
    }
}

extern "C" void kernel_launch(void* const* d_in, const int* in_sizes, int n_in,
                              void* d_out, int out_size, void* d_ws, size_t ws_size,
                              hipStream_t stream) {
    const int* log_seqs   = (const int*)d_in[1];
    const int* tm         = (const int*)d_in[2];
    const int* pos_seqs   = (const int*)d_in[3];
    const int* neg_seqs   = (const int*)d_in[4];
    const float* item_emb = (const float*)d_in[5];
    const float* posK     = (const float*)d_in[6];
    const float* posV     = (const float*)d_in[7];
    const float* timeK    = (const float*)d_in[8];
    const float* timeV    = (const float*)d_in[9];
    const float* attn_g   = (const float*)d_in[10];
    const float* attn_b   = (const float*)d_in[11];
    const float* Wq       = (const float*)d_in[12];
    const float* bq       = (const float*)d_in[13];
    const float* Wk       = (const float*)d_in[14];
    const float* bk       = (const float*)d_in[15];
    const float* Wv       = (const float*)d_in[16];
    const float* bv       = (const float*)d_in[17];
    const float* fwd_g    = (const float*)d_in[18];
    const float* fwd_b    = (const float*)d_in[19];
    const float* W1       = (const float*)d_in[20];
    const float* b1       = (const float*)d_in[21];
    const float* W2       = (const float*)d_in[22];
    const float* b2       = (const float*)d_in[23];
    const float* last_g   = (const float*)d_in[24];
    const float* last_b   = (const float*)d_in[25];

    float* seqs = (float*)d_ws;            // 7 x B*L*H f32 = ~5.7 MB
    float* Qin  = seqs + (size_t)BL * HH;
    float* Qb   = Qin  + (size_t)BL * HH;
    float* Kb   = Qb   + (size_t)BL * HH;
    float* Vb   = Kb   + (size_t)BL * HH;
    float* att  = Vb   + (size_t)BL * HH;
    float* h1   = att  + (size_t)BL * HH;

    for (int i = 0; i < NBLK; i++) {
        k_qkv_gemm<<<1200, 256, 0, stream>>>(i == 0 ? nullptr : seqs, log_seqs, item_emb,
                                             attn_g + i * HH, attn_b + i * HH,
                                             Wq + (size_t)i * HH * HH, bq + i * HH,
                                             Wk + (size_t)i * HH * HH, bk + i * HH,
                                             Wv + (size_t)i * HH * HH, bv + i * HH,
                                             posK, posV, Qin, Qb, Kb, Vb);
        k_attn<<<NQT * 32, 256, 0, stream>>>(Qb, Kb, Vb, timeK, timeV, tm, att);
        k_ff1<<<800, 256, 0, stream>>>(Qin, att, fwd_g + i * HH, fwd_b + i * HH,
                                       W1 + (size_t)i * HH * HH, b1 + i * HH, h1);
        k_ff2<<<800, 256, 0, stream>>>(h1, Qin, att, fwd_g + i * HH, fwd_b + i * HH,
                                       W2 + (size_t)i * HH * HH, b2 + i * HH,
                                       log_seqs, seqs);
    }
    k_lnlogits<<<BL, HH, 0, stream>>>(seqs, last_g, last_b, item_emb,
                                      pos_seqs, neg_seqs, (float*)d_out);
}